// Round 1
// 149.352 us; speedup vs baseline: 1.0165x; 1.0165x over previous
//
#include <hip/hip_runtime.h>

typedef __bf16 bf16_t;
typedef __bf16 bf16x4_t __attribute__((ext_vector_type(4)));
typedef __bf16 bf16x8 __attribute__((ext_vector_type(8)));
typedef float f32x4 __attribute__((ext_vector_type(4)));

#define NH 8
#define DH 32
#define QL 256
#define KL 256
#define CIN 64
#define HD 256  // NH*DH

__device__ __forceinline__ bf16_t f2bf(float x) { return (bf16_t)x; }

__device__ __forceinline__ f32x4 mfma16(bf16x8 a, bf16x8 b, f32x4 c) {
    return __builtin_amdgcn_mfma_f32_16x16x32_bf16(a, b, c, 0, 0, 0);
}

// ---------------------------------------------------------------------------
// pack_w: one-time repack of Wq/Wk/Wv/Wo into fragment-native bf16 layout.
// Per head: 4 frags per W (nt*2+ks for the 64-K projections; nt 0..3 for Wo).
// Frag elem j at lane(quad,l16):
//   WqF/WkF/WvF: W[ks*32+quad*8+j][h*32 + nt*16 + l16]   (B-operand, proj)
//   WoF:         Wo[h*32+quad*8+j][nt*16 + l16]          (B-operand, outproj)
// Grid: 8 blocks (h) x 4 waves (wave = which matrix).
__launch_bounds__(256)
__global__ void pack_w(const float* __restrict__ Wq, const float* __restrict__ Wk,
                       const float* __restrict__ Wv, const float* __restrict__ Wo,
                       bf16_t* __restrict__ WqF, bf16_t* __restrict__ WkF,
                       bf16_t* __restrict__ WvF, bf16_t* __restrict__ WoF) {
    const int h = blockIdx.x;
    const int tid = threadIdx.x, lane = tid & 63, w = tid >> 6;
    const int quad = lane >> 4, l16 = lane & 15;
    if (w < 3) {
        const float* __restrict__ W = (w == 0) ? Wq : (w == 1 ? Wk : Wv);
        bf16_t* __restrict__ F = (w == 0) ? WqF : (w == 1 ? WkF : WvF);
#pragma unroll
        for (int nt = 0; nt < 2; ++nt)
#pragma unroll
            for (int ks = 0; ks < 2; ++ks) {
                bf16x8 f;
#pragma unroll
                for (int j = 0; j < 8; ++j)
                    f[j] = f2bf(W[(ks * 32 + quad * 8 + j) * HD + h * DH + nt * 16 + l16]);
                *(bf16x8*)&F[(size_t)((h * 4 + nt * 2 + ks) * 512) + lane * 8] = f;
            }
    } else {
#pragma unroll
        for (int nt = 0; nt < 4; ++nt) {
            bf16x8 f;
#pragma unroll
            for (int j = 0; j < 8; ++j)
                f[j] = f2bf(Wo[(h * DH + quad * 8 + j) * CIN + nt * 16 + l16]);
            *(bf16x8*)&WoF[(size_t)((h * 4 + nt) * 512) + lane * 8] = f;
        }
    }
}

// ---------------------------------------------------------------------------
// fused_attn: one block = (s, 64-q-row quarter). The full pipeline
// (proj -> attention -> outproj-accumulate) runs per head with K/V living
// only in LDS; no intermediate ever touches global memory.
//   - X frags register-resident (reused all 8 heads); Q pre-scaled.
//   - sK row-major [256][40]  : stride 20 dw (gcd 4 with 32) -> b128 reads at
//     the 8-cycle LDS floor. C/D -> scalar bf16 stores (natural layout).
//   - sVT transposed [32][264]: stride 132 dw == 4 mod 32; V C/D rows pack to
//     ds_write_b64 along kv.
//   - sB per-wave bounce [16][136] (stride 68 dw == 4): Q/O C/D->A-frag
//     repack and P^T staging (same-wave DS ordering, no barriers).
//   - 2 barriers/head; LDS 54.5 KB -> 2 blocks/CU hide each other's drains.
//   - Bias loads issued mid-proj so latency hides under V/Q MFMAs; mask
//     pre-combined once per block into sMask.
__launch_bounds__(256, 2)
__global__ void fused_attn(const float* __restrict__ Xq, const float* __restrict__ Xkv,
                           const float* __restrict__ Mask, const float* __restrict__ Bias,
                           const bf16_t* __restrict__ WqF, const bf16_t* __restrict__ WkF,
                           const bf16_t* __restrict__ WvF, const bf16_t* __restrict__ WoF,
                           const float* __restrict__ Bo, float* __restrict__ Out) {
    const int b = blockIdx.x;
    const int s = b & 127, qq = b >> 7;  // s fastest: same-s quarters land on one XCD
    const int tid = threadIdx.x, lane = tid & 63, w = tid >> 6;
    const int quad = lane >> 4, l16 = lane & 15;
    const int tg = qq * 4 + w;  // this wave's global q-tile (16 rows)
    const f32x4 vzero = {0.f, 0.f, 0.f, 0.f};

    __shared__ __attribute__((aligned(16))) bf16_t sK[KL][40];    // 20.0 KB
    __shared__ __attribute__((aligned(16))) bf16_t sVT[DH][264];  // 16.5 KB
    __shared__ __attribute__((aligned(16))) bf16_t sB[4][16][136];// 17.0 KB
    __shared__ __attribute__((aligned(16))) float sMask[KL];      //  1.0 KB

    // mask pre-combined: (m-1)*INF, shared by all heads/q of this s
    if (tid < 64) {
        const f32x4 m4 = *(const f32x4*)&Mask[s * KL + tid * 4];
        f32x4 mm;
#pragma unroll
        for (int j = 0; j < 4; ++j) mm[j] = (m4[j] - 1.0f) * 1.0e9f;
        *(f32x4*)&sMask[tid * 4] = mm;
    }

    // ---- X fragments, register-resident for all 8 heads ----
    bf16x8 xk[4][2];  // Xkv A-frags: wave owns kv-tiles {4w..4w+3}
#pragma unroll
    for (int t = 0; t < 4; ++t) {
        const int row = (w * 4 + t) * 16 + l16;
        const float* src = &Xkv[(size_t)(s * QL + row) * CIN];
#pragma unroll
        for (int ks = 0; ks < 2; ++ks) {
            const f32x4 lo = *(const f32x4*)&src[ks * 32 + quad * 8];
            const f32x4 hi = *(const f32x4*)&src[ks * 32 + quad * 8 + 4];
            bf16x8 f;
#pragma unroll
            for (int j = 0; j < 4; ++j) { f[j] = f2bf(lo[j]); f[4 + j] = f2bf(hi[j]); }
            xk[t][ks] = f;
        }
    }
    bf16x8 xq[2];  // Xq A-frags for this wave's q-tile, pre-scaled 1/sqrt(32)
    {
        const int row = tg * 16 + l16;
        const float* src = &Xq[(size_t)(s * QL + row) * CIN];
#pragma unroll
        for (int ks = 0; ks < 2; ++ks) {
            const f32x4 lo = *(const f32x4*)&src[ks * 32 + quad * 8];
            const f32x4 hi = *(const f32x4*)&src[ks * 32 + quad * 8 + 4];
            bf16x8 f;
#pragma unroll
            for (int j = 0; j < 4; ++j) {
                f[j] = f2bf(lo[j] * 0.17677669529663687f);
                f[4 + j] = f2bf(hi[j] * 0.17677669529663687f);
            }
            xq[ks] = f;
        }
    }

    f32x4 acc[4];  // output accumulator: 16 q-rows x 64 out-cols
#pragma unroll
    for (int nt = 0; nt < 4; ++nt) acc[nt] = vzero;

#pragma unroll 1
    for (int h = 0; h < NH; ++h) {
        // -------------------- proj phase --------------------
        bf16x8 bk[2][2], bv[2][2];
#pragma unroll
        for (int nt = 0; nt < 2; ++nt)
#pragma unroll
            for (int ks = 0; ks < 2; ++ks) {
                bk[nt][ks] = *(const bf16x8*)&WkF[(size_t)((h * 4 + nt * 2 + ks) * 512) + lane * 8];
                bv[nt][ks] = *(const bf16x8*)&WvF[(size_t)((h * 4 + nt * 2 + ks) * 512) + lane * 8];
            }
        // K: C/D (row=quad*4+r, d=nt*16+l16) -> sK row-major (attn A-frag layout)
#pragma unroll
        for (int t = 0; t < 4; ++t) {
            const int r0 = (w * 4 + t) * 16 + quad * 4;
#pragma unroll
            for (int nt = 0; nt < 2; ++nt) {
                f32x4 c = mfma16(xk[t][0], bk[nt][0], vzero);
                c = mfma16(xk[t][1], bk[nt][1], c);
#pragma unroll
                for (int r = 0; r < 4; ++r) sK[r0 + r][nt * 16 + l16] = f2bf(c[r]);
            }
        }
        // bias rides in early: 16 f32x4, latency hides under V/Q proj
        f32x4 sv[16];
        const float* bb = &Bias[(size_t)(h * QL + tg * 16 + l16) * KL];
#pragma unroll
        for (int ct = 0; ct < 16; ++ct) sv[ct] = *(const f32x4*)&bb[ct * 16 + quad * 4];
        // V: C/D rows are kv -> transpose-store to sVT[d][kv] as b64 packs
#pragma unroll
        for (int t = 0; t < 4; ++t) {
            const int c0 = (w * 4 + t) * 16 + quad * 4;
#pragma unroll
            for (int nt = 0; nt < 2; ++nt) {
                f32x4 c = mfma16(xk[t][0], bv[nt][0], vzero);
                c = mfma16(xk[t][1], bv[nt][1], c);
                bf16x4_t p;
#pragma unroll
                for (int r = 0; r < 4; ++r) p[r] = f2bf(c[r]);
                *(bf16x4_t*)&sVT[nt * 16 + l16][c0] = p;
            }
        }
        // Q: C/D -> per-wave bounce -> B-frag (same-wave DS order, no barrier)
        {
            bf16x8 bq[2][2];
#pragma unroll
            for (int nt = 0; nt < 2; ++nt)
#pragma unroll
                for (int ks = 0; ks < 2; ++ks)
                    bq[nt][ks] = *(const bf16x8*)&WqF[(size_t)((h * 4 + nt * 2 + ks) * 512) + lane * 8];
#pragma unroll
            for (int nt = 0; nt < 2; ++nt) {
                f32x4 c = mfma16(xq[0], bq[nt][0], vzero);
                c = mfma16(xq[1], bq[nt][1], c);
#pragma unroll
                for (int r = 0; r < 4; ++r) sB[w][quad * 4 + r][nt * 16 + l16] = f2bf(c[r]);
            }
        }
        const bf16x8 qfr = *(const bf16x8*)&sB[w][l16][quad * 8];

        __syncthreads();  // barrier 1: sK/sVT of head h visible

        // -------------------- attn phase --------------------
#pragma unroll
        for (int ct = 0; ct < 16; ++ct)
            sv[ct] += *(const f32x4*)&sMask[ct * 16 + quad * 4];  // broadcast read
        // S' = K·Q^T rides the C operand: C/D row=kv-local, col=q
#pragma unroll
        for (int ct = 0; ct < 16; ++ct) {
            const bf16x8 ak = *(const bf16x8*)&sK[ct * 16 + l16][quad * 8];
            sv[ct] = mfma16(ak, qfr, sv[ct]);
        }
        // softmax over kv: 64 per-lane values + xor 16/32 across quads
        float mx = -1e30f;
#pragma unroll
        for (int ct = 0; ct < 16; ++ct)
#pragma unroll
            for (int r = 0; r < 4; ++r) mx = fmaxf(mx, sv[ct][r]);
        mx = fmaxf(mx, __shfl_xor(mx, 16, 64));
        mx = fmaxf(mx, __shfl_xor(mx, 32, 64));
        float sum = 0.f;
#pragma unroll
        for (int ct = 0; ct < 16; ++ct)
#pragma unroll
            for (int r = 0; r < 4; ++r) {
                const float e = __expf(sv[ct][r] - mx);
                sv[ct][r] = e;
                sum += e;
            }
        sum += __shfl_xor(sum, 16, 64);
        sum += __shfl_xor(sum, 32, 64);
        const float rs = 1.0f / sum;

        // PV in two 128-kv chunks: P^T -> sB -> A-frags; V from sVT
        f32x4 o0 = vzero, o1 = vzero;
#pragma unroll
        for (int c = 0; c < 2; ++c) {
#pragma unroll
            for (int cc = 0; cc < 8; ++cc) {
                const int ct = c * 8 + cc;
                bf16x4_t pv;
#pragma unroll
                for (int r = 0; r < 4; ++r) pv[r] = f2bf(sv[ct][r] * rs);
                *(bf16x4_t*)&sB[w][l16][cc * 16 + quad * 4] = pv;
            }
#pragma unroll
            for (int ks = 0; ks < 4; ++ks) {
                const bf16x8 ap = *(const bf16x8*)&sB[w][l16][ks * 32 + quad * 8];
                const int cs = c * 4 + ks;
                const bf16x8 v0 = *(const bf16x8*)&sVT[l16][cs * 32 + quad * 8];
                const bf16x8 v1 = *(const bf16x8*)&sVT[16 + l16][cs * 32 + quad * 8];
                o0 = mfma16(ap, v0, o0);
                o1 = mfma16(ap, v1, o1);
            }
        }

        __syncthreads();  // barrier 2: sK/sVT free for head h+1

        // ---------- outproj accumulate (sB is per-wave: overlaps next proj) ----------
        {
            bf16x8 bwo[4];
#pragma unroll
            for (int nt = 0; nt < 4; ++nt)
                bwo[nt] = *(const bf16x8*)&WoF[(size_t)((h * 4 + nt) * 512) + lane * 8];
#pragma unroll
            for (int r = 0; r < 4; ++r) {
                sB[w][quad * 4 + r][l16] = f2bf(o0[r]);
                sB[w][quad * 4 + r][16 + l16] = f2bf(o1[r]);
            }
            const bf16x8 af = *(const bf16x8*)&sB[w][l16][quad * 8];
#pragma unroll
            for (int nt = 0; nt < 4; ++nt) acc[nt] = mfma16(af, bwo[nt], acc[nt]);
        }
    }

    // -------------------- epilogue --------------------
    const int orow = s * QL + tg * 16 + quad * 4;
#pragma unroll
    for (int nt = 0; nt < 4; ++nt) {
        const float bo = Bo[nt * 16 + l16];
#pragma unroll
        for (int r = 0; r < 4; ++r)
            Out[(size_t)(orow + r) * CIN + nt * 16 + l16] = acc[nt][r] + bo;
    }
}

extern "C" void kernel_launch(void* const* d_in, const int* in_sizes, int n_in,
                              void* d_out, int out_size, void* d_ws, size_t ws_size,
                              hipStream_t stream) {
    const float* Xq   = (const float*)d_in[0];
    const float* Xkv  = (const float*)d_in[1];
    const float* Mask = (const float*)d_in[2];
    const float* Bias = (const float*)d_in[3];
    const float* Wq   = (const float*)d_in[4];
    const float* Wk   = (const float*)d_in[5];
    const float* Wv   = (const float*)d_in[6];
    const float* Wo   = (const float*)d_in[7];
    const float* Bo   = (const float*)d_in[8];
    float* Out = (float*)d_out;

    // 128 KB of fragment-native weights at the head of ws (ws >= 48 MB proven)
    bf16_t* WqF = (bf16_t*)d_ws;
    bf16_t* WkF = WqF + 16384;
    bf16_t* WvF = WkF + 16384;
    bf16_t* WoF = WvF + 16384;

    pack_w<<<dim3(NH), 256, 0, stream>>>(Wq, Wk, Wv, Wo, WqF, WkF, WvF, WoF);
    fused_attn<<<dim3(512), 256, 0, stream>>>(Xq, Xkv, Mask, Bias,
                                              WqF, WkF, WvF, WoF, Bo, Out);
}